// Round 5
// baseline (236.073 us; speedup 1.0000x reference)
//
#include <hip/hip_runtime.h>
#include <hip/hip_bf16.h>

// Problem constants
#define B_  8
#define S_  2048
#define H_  1024
#define P_  4096
#define K_  2048   // 2*H
#define M_  32768  // B*P
#define NT_ 32     // K-tiles (BK=64)

typedef unsigned short u16;
using bf16x8 = __attribute__((ext_vector_type(8))) short;   // 8 bf16 = 4 VGPRs
using f32x4  = __attribute__((ext_vector_type(4))) float;

#define AS1 __attribute__((address_space(1)))
#define AS3 __attribute__((address_space(3)))

__device__ inline u16 f2bf(float f) {
  union { float f; unsigned u; } c; c.f = f;
  unsigned u = c.u;
  unsigned r = (u + 0x7fffu + ((u >> 16) & 1u)) >> 16;  // RNE
  return (u16)r;
}

// ---- prep 1: hidden fp32 -> bf16 ---------------------------------------
__global__ void cvt_hidden_k(const float4* __restrict__ src,
                             ushort4* __restrict__ dst, int n4) {
  int i = blockIdx.x * blockDim.x + threadIdx.x;
  int stride = gridDim.x * blockDim.x;
  for (; i < n4; i += stride) {
    float4 v = src[i];
    ushort4 o;
    o.x = f2bf(v.x); o.y = f2bf(v.y); o.z = f2bf(v.z); o.w = f2bf(v.w);
    dst[i] = o;
  }
}

// ---- prep 2: W1 (K x N fp32, k-major) -> W1T (N x K bf16) ---------------
__global__ void transp_w1_k(const float* __restrict__ w1, u16* __restrict__ w1t) {
  __shared__ float tile[32][33];
  int n0 = blockIdx.x * 32;
  int k0 = blockIdx.y * 32;
  int tx = threadIdx.x;   // 0..31
  int ty = threadIdx.y;   // 0..7
#pragma unroll
  for (int i = 0; i < 32; i += 8)
    tile[ty + i][tx] = w1[(size_t)(k0 + ty + i) * H_ + n0 + tx];
  __syncthreads();
#pragma unroll
  for (int i = 0; i < 32; i += 8)
    w1t[(size_t)(n0 + ty + i) * K_ + k0 + tx] = f2bf(tile[tx][ty + i]);
}

// ---- main fused gather-GEMM + GELU + W2 partial contraction -------------
// 256x256 tile, BK=64, 8 waves (2M x 4N). A (gathered) staged via LDS
// 3-region ring (stage t+2 during t); B loaded DIRECT to registers
// (double-buffered one tile ahead). ONE vmcnt(0)+barrier per K-tile;
// no intra-tile barriers -> waves drift, LDS/MFMA/VMEM overlap naturally.
// 512 blocks, XCD-swizzled: each XCD gathers from one batch (4MB = one L2).
__global__ __launch_bounds__(512, 2) void gemm_k(
    const u16*  __restrict__ hidB,   // bf16 hidden [B][S][H]
    const u16*  __restrict__ w1t,    // bf16 W1^T   [N=1024][K=2048]
    const int*  __restrict__ pairs,  // int32 [B][P][2]
    const float* __restrict__ b1,
    const float2* __restrict__ w2,   // W2 rows as float2
    float*      __restrict__ part)   // [16 q][32768 m] float2
{
  __shared__ u16 lds[3 * 16384];   // 3 A-regions x 32KB = 96KB

  // XCD-aware bijective swizzle (512 % 8 == 0)
  int orig = blockIdx.x;
  int bid = (orig & 7) * 64 + (orig >> 3);
  int nt = bid & 3;
  int mt = bid >> 2;
  int n0 = nt * 256;
  int m0 = mt * 256;
  int bI = m0 >> 12;       // batch index (256 | 4096)
  int pp = m0 & 4095;

  int t = threadIdx.x;
  int w = t >> 6;          // wave 0..7
  int l = t & 63;
  int lr = l & 15;
  int lj = l >> 4;
  int wr = w >> 2;         // wave row (M): 0..1 -> 128 rows each
  int wn = w & 3;          // wave col (N): 0..3 -> 64 cols each

  // staging: source granule swizzle (involution; read side applies same XOR)
  int gsrc = (l & 7) ^ ((l >> 3) & 7);

  // gather indices for the 4 staged rows: r_i = w*32 + i*8 + (l>>3)
  int2 sv[4];
#pragma unroll
  for (int i = 0; i < 4; ++i)
    sv[i] = ((const int2*)pairs)[bI * P_ + pp + w * 32 + i * 8 + (l >> 3)];

  const u16* hidBase = hidB + ((size_t)bI << 21);            // b * S_*H_
  const u16* bRowBase = w1t + (size_t)(n0 + wn * 64 + lr) * K_;

  f32x4 acc[8][4];
#pragma unroll
  for (int i = 0; i < 8; ++i)
#pragma unroll
    for (int j = 0; j < 4; ++j)
      acc[i][j] = (f32x4){0.f, 0.f, 0.f, 0.f};

  // stage A region for K-tile `tile` (4 x global_load_lds, 1KB each)
  auto STAGE = [&](int tile) {
    if (tile >= NT_) return;
    unsigned reg = (unsigned)(tile % 3) * 16384u;
    int k0 = tile * 64;
    int kcol = k0 & 1023;     // column within selected half-row
    int half = k0 >> 10;      // 0 -> emb1, 1 -> emb2
#pragma unroll
    for (int i = 0; i < 4; ++i) {
      int s = half ? sv[i].y : sv[i].x;
      __builtin_amdgcn_global_load_lds(
          (const AS1 void*)(hidBase + (((size_t)s) << 10) + kcol + gsrc * 8),
          (AS3 void*)&lds[reg + (unsigned)(w * 32 + i * 8) * 64u + (unsigned)l * 8u],
          16, 0, 0);
    }
  };

// load B fragments for K-tile TB into register set BV[2][4]
#define LOADB(BV, TB)                                                         \
  {                                                                           \
    int tb_ = (TB) < NT_ ? (TB) : NT_ - 1;                                    \
    int kb_ = tb_ * 64;                                                       \
    _Pragma("unroll")                                                         \
    for (int ks = 0; ks < 2; ++ks)                                            \
      _Pragma("unroll")                                                       \
      for (int ni = 0; ni < 4; ++ni)                                          \
        BV[ks][ni] = *(const bf16x8*)(bRowBase + (size_t)ni * 16 * K_ +       \
                                      kb_ + ks * 32 + lj * 8);                \
  }

// one K-tile: boundary sync, stage t+2, prefetch B(t+1), 4 x 16-MFMA clusters
#define TILE(TI, BVU, BVN)                                                    \
  {                                                                           \
    const int ti_ = (TI);                                                     \
    asm volatile("s_waitcnt vmcnt(0)" ::: "memory");                          \
    __builtin_amdgcn_s_barrier();                                             \
    STAGE(ti_ + 2);                                                           \
    LOADB(BVN, ti_ + 1);                                                      \
    unsigned reg_ = (unsigned)(ti_ % 3) * 16384u;                             \
    _Pragma("unroll")                                                         \
    for (int ks = 0; ks < 2; ++ks) {                                          \
      _Pragma("unroll")                                                       \
      for (int MH = 0; MH < 2; ++MH) {                                        \
        bf16x8 af[4];                                                         \
        _Pragma("unroll")                                                     \
        for (int mi = 0; mi < 4; ++mi)                                        \
          af[mi] = *(const bf16x8*)&lds[reg_ +                                \
              (unsigned)(wr * 128 + MH * 64 + mi * 16 + lr) * 64u +           \
              (unsigned)(((ks * 4 + lj) ^ (lr & 7)) * 8)];                    \
        __builtin_amdgcn_s_setprio(1);                                        \
        _Pragma("unroll")                                                     \
        for (int mi = 0; mi < 4; ++mi)                                        \
          _Pragma("unroll")                                                   \
          for (int ni = 0; ni < 4; ++ni)                                      \
            acc[MH * 4 + mi][ni] = __builtin_amdgcn_mfma_f32_16x16x32_bf16(   \
                af[mi], BVU[ks][ni], acc[MH * 4 + mi][ni], 0, 0, 0);          \
        __builtin_amdgcn_s_setprio(0);                                        \
      }                                                                       \
    }                                                                         \
  }

  bf16x8 bvA[2][4], bvB[2][4];

  // prologue: regions 0,1 in flight; B(0) in flight
  STAGE(0); STAGE(1);
  LOADB(bvA, 0);

  for (int u = 0; u < NT_ / 2; ++u) {
    TILE(2 * u,     bvA, bvB);
    TILE(2 * u + 1, bvB, bvA);
  }
#undef TILE
#undef LOADB

  // ---- fused epilogue: bias + exact GELU + W2 contraction ----
  // acc element (I,ni,j): row = wr*128 + I*16 + lj*4 + j, col = wn*64+ni*16+lr
  int q = nt * 4 + wn;
  float2* pOut = (float2*)part;
#pragma unroll
  for (int mi = 0; mi < 8; ++mi) {
    float s0[4] = {0.f, 0.f, 0.f, 0.f};
    float s1[4] = {0.f, 0.f, 0.f, 0.f};
#pragma unroll
    for (int ni = 0; ni < 4; ++ni) {
      int n = n0 + wn * 64 + ni * 16 + lr;
      float bb = b1[n];
      float2 wv = w2[n];
#pragma unroll
      for (int j = 0; j < 4; ++j) {
        float x = acc[mi][ni][j] + bb;
        float g = 0.5f * x * (1.0f + erff(x * 0.70710678118654752f));
        s0[j] += g * wv.x;
        s1[j] += g * wv.y;
      }
    }
#pragma unroll
    for (int off = 1; off < 16; off <<= 1) {
#pragma unroll
      for (int j = 0; j < 4; ++j) {
        s0[j] += __shfl_xor(s0[j], off, 64);
        s1[j] += __shfl_xor(s1[j], off, 64);
      }
    }
    if (lr == 0) {
#pragma unroll
      for (int j = 0; j < 4; ++j) {
        int m = m0 + wr * 128 + mi * 16 + lj * 4 + j;
        pOut[((size_t)q << 15) + m] = make_float2(s0[j], s1[j]);
      }
    }
  }
}

// ---- final reduce over 16 partials + b2 ---------------------------------
__global__ void reduce_k(const float2* __restrict__ part,
                         const float* __restrict__ b2,
                         float2* __restrict__ out) {
  int m = blockIdx.x * blockDim.x + threadIdx.x;
  if (m >= M_) return;
  float a0 = b2[0], a1 = b2[1];
#pragma unroll
  for (int q = 0; q < 16; ++q) {
    float2 v = part[((size_t)q << 15) + m];
    a0 += v.x; a1 += v.y;
  }
  out[m] = make_float2(a0, a1);
}

extern "C" void kernel_launch(void* const* d_in, const int* in_sizes, int n_in,
                              void* d_out, int out_size, void* d_ws, size_t ws_size,
                              hipStream_t stream) {
  const float* hidden = (const float*)d_in[0];
  const int*   pairs  = (const int*)d_in[1];
  const float* W1     = (const float*)d_in[2];
  const float* b1     = (const float*)d_in[3];
  const float* W2     = (const float*)d_in[4];
  const float* b2     = (const float*)d_in[5];
  float* out = (float*)d_out;

  // ws layout: hidden_bf16 (32 MiB) | W1T_bf16 (4 MiB) | partials (4 MiB)
  u16* hidB = (u16*)d_ws;
  u16* w1t  = hidB + (size_t)B_ * S_ * H_;
  float* part = (float*)(w1t + (size_t)H_ * K_);

  int n4 = (B_ * S_ * H_) / 4;
  cvt_hidden_k<<<4096, 256, 0, stream>>>((const float4*)hidden, (ushort4*)hidB, n4);
  transp_w1_k<<<dim3(H_ / 32, K_ / 32), dim3(32, 8), 0, stream>>>(W1, w1t);
  gemm_k<<<(M_ / 256) * (H_ / 256), 512, 0, stream>>>(
      hidB, w1t, pairs, b1, (const float2*)W2, part);
  reduce_k<<<(M_ + 255) / 256, 256, 0, stream>>>(
      (const float2*)part, b2, (float2*)out);
}

// Round 6
// 174.354 us; speedup vs baseline: 1.3540x; 1.3540x over previous
//
#include <hip/hip_runtime.h>
#include <hip/hip_bf16.h>

// Problem constants
#define B_  8
#define S_  2048
#define H_  1024
#define P_  4096
#define K_  2048   // 2*H
#define M_  32768  // B*P

typedef unsigned short u16;
using bf16x8 = __attribute__((ext_vector_type(8))) short;   // 8 bf16 = 4 VGPRs
using f32x4  = __attribute__((ext_vector_type(4))) float;

#define AS1 __attribute__((address_space(1)))
#define AS3 __attribute__((address_space(3)))

__device__ inline u16 f2bf(float f) {
  union { float f; unsigned u; } c; c.f = f;
  unsigned u = c.u;
  unsigned r = (u + 0x7fffu + ((u >> 16) & 1u)) >> 16;  // RNE
  return (u16)r;
}

// ---- prep 1: hidden fp32 -> bf16 ---------------------------------------
__global__ void cvt_hidden_k(const float4* __restrict__ src,
                             ushort4* __restrict__ dst, int n4) {
  int i = blockIdx.x * blockDim.x + threadIdx.x;
  int stride = gridDim.x * blockDim.x;
  for (; i < n4; i += stride) {
    float4 v = src[i];
    ushort4 o;
    o.x = f2bf(v.x); o.y = f2bf(v.y); o.z = f2bf(v.z); o.w = f2bf(v.w);
    dst[i] = o;
  }
}

// ---- prep 2: W1 (K x N fp32, k-major) -> W1T (N x K bf16) ---------------
__global__ void transp_w1_k(const float* __restrict__ w1, u16* __restrict__ w1t) {
  __shared__ float tile[32][33];
  int n0 = blockIdx.x * 32;
  int k0 = blockIdx.y * 32;
  int tx = threadIdx.x;   // 0..31
  int ty = threadIdx.y;   // 0..7
#pragma unroll
  for (int i = 0; i < 32; i += 8)
    tile[ty + i][tx] = w1[(size_t)(k0 + ty + i) * H_ + n0 + tx];
  __syncthreads();
#pragma unroll
  for (int i = 0; i < 32; i += 8)
    w1t[(size_t)(n0 + ty + i) * K_ + k0 + tx] = f2bf(tile[tx][ty + i]);
}

// ---- main fused gather-GEMM + GELU + W2 partial contraction -------------
// 256x256 tile, BK=64 as 2 k-slices of 32, 8 waves (2M x 4N).
// 4 phases per 2 K-tiles (32 MFMA per cluster): {12 ds_read | stage A+B
// region pair (4 gloads, depth-3) | vmcnt(8) | barrier | lgkmcnt(0) |
// 32 MFMA w/ setprio | barrier}. 8 x 16KB LDS ring = 128 KB.
// 512 blocks, XCD-swizzled: each XCD gathers from one batch (4MB = one L2).
__global__ __launch_bounds__(512, 2) void gemm_k(
    const u16*  __restrict__ hidB,   // bf16 hidden [B][S][H]
    const u16*  __restrict__ w1t,    // bf16 W1^T   [N=1024][K=2048]
    const int*  __restrict__ pairs,  // int32 [B][P][2]
    const float* __restrict__ b1,
    const float2* __restrict__ w2,   // W2 rows as float2
    float*      __restrict__ part)   // [16 q][32768 m] float2
{
  __shared__ u16 lds[65536];   // 8 regions x 16KB = 128 KB

#define REG(SLOT, KS, AB) ((((SLOT)*2 + (KS))*2 + (AB)) * 8192)

  // XCD-aware bijective swizzle (512 % 8 == 0)
  int orig = blockIdx.x;
  int bid = (orig & 7) * 64 + (orig >> 3);
  int nt = bid & 3;
  int mt = bid >> 2;
  int n0 = nt * 256;
  int m0 = mt * 256;
  int bI = m0 >> 12;       // batch index (256 | 4096)
  int pp = m0 & 4095;

  int t = threadIdx.x;
  int w = t >> 6;          // wave 0..7
  int l = t & 63;
  int lr = l & 15;
  int lj = l >> 4;
  int wr = w >> 2;         // wave row (M): 0..1 -> 128 rows each
  int wn = w & 3;          // wave col (N): 0..3 -> 64 cols each

  // LDS read slot (16B granule within 64B row), lane-constant:
  // slot = lj ^ ((row>>1)&3) and (row>>1)&3 == (l>>1)&3 for all our rows
  int slot8 = (lj ^ ((l >> 1) & 3)) * 8;   // u16 offset
  // staging source granule (write side of the same involution)
  int gsrc = (l & 3) ^ ((l >> 3) & 3);

  // staging rows owned by this thread (2 rows per region, 2 gloads)
  int r0 = w * 16 + (l >> 2);        // 0..127
  int r1 = 128 + r0;                 // 128..255

  int2 sv0 = ((const int2*)pairs)[bI * P_ + pp + r0];
  int2 sv1 = ((const int2*)pairs)[bI * P_ + pp + r1];

  const u16* hidBase = hidB + ((size_t)bI << 21);  // b * S_*H_

  f32x4 acc[8][4];
#pragma unroll
  for (int i = 0; i < 8; ++i)
#pragma unroll
    for (int j = 0; j < 4; ++j)
      acc[i][j] = (f32x4){0.f, 0.f, 0.f, 0.f};

  // stage one A region (256 rows x 32 k) = 2 x global_load_lds
  auto STAGE_A = [&](int base, int tile, int ks) {
    int k = tile * 64 + ks * 32;
    int kcol = k & 1023;
    int half = k >> 10;
    int sA0 = half ? sv0.y : sv0.x;
    int sA1 = half ? sv1.y : sv1.x;
    int dst = base + w * 512 + l * 8;
    __builtin_amdgcn_global_load_lds(
        (const AS1 void*)(hidBase + (((size_t)sA0) << 10) + kcol + gsrc * 8),
        (AS3 void*)&lds[dst], 16, 0, 0);
    __builtin_amdgcn_global_load_lds(
        (const AS1 void*)(hidBase + (((size_t)sA1) << 10) + kcol + gsrc * 8),
        (AS3 void*)&lds[dst + 4096], 16, 0, 0);
  };
  // stage one B region
  auto STAGE_B = [&](int base, int tile, int ks) {
    int k = tile * 64 + ks * 32;
    int dst = base + w * 512 + l * 8;
    __builtin_amdgcn_global_load_lds(
        (const AS1 void*)(w1t + (size_t)(n0 + r0) * K_ + k + gsrc * 8),
        (AS3 void*)&lds[dst], 16, 0, 0);
    __builtin_amdgcn_global_load_lds(
        (const AS1 void*)(w1t + (size_t)(n0 + r1) * K_ + k + gsrc * 8),
        (AS3 void*)&lds[dst + 4096], 16, 0, 0);
  };

#define VM8 asm volatile("s_waitcnt vmcnt(8)" ::: "memory")
#define VM4 asm volatile("s_waitcnt vmcnt(4)" ::: "memory")
#define VM0 asm volatile("s_waitcnt vmcnt(0)" ::: "memory")

// one phase: {8 af + 4 bv ds_reads | stage A+B of phase p+3 | counted wait |
//             barrier | lgkmcnt(0) | 32 MFMA | barrier}
#define PHASE(SLOT, KS, STAGEOP, WAITOP)                                       \
  {                                                                            \
    bf16x8 af[2][4], bv[4];                                                    \
    _Pragma("unroll")                                                          \
    for (int MH = 0; MH < 2; ++MH)                                             \
      _Pragma("unroll")                                                        \
      for (int mi = 0; mi < 4; ++mi)                                           \
        af[MH][mi] = *(const bf16x8*)&lds[REG(SLOT, KS, 0) +                   \
            (wr * 128 + MH * 64 + mi * 16 + lr) * 32 + slot8];                 \
    _Pragma("unroll")                                                          \
    for (int ni = 0; ni < 4; ++ni)                                             \
      bv[ni] = *(const bf16x8*)&lds[REG(SLOT, KS, 1) +                         \
          (wn * 64 + ni * 16 + lr) * 32 + slot8];                              \
    STAGEOP;                                                                   \
    WAITOP;                                                                    \
    __builtin_amdgcn_s_barrier();                                              \
    asm volatile("s_waitcnt lgkmcnt(0)" ::: "memory");                         \
    __builtin_amdgcn_sched_barrier(0);                                         \
    __builtin_amdgcn_s_setprio(1);                                             \
    _Pragma("unroll")                                                          \
    for (int MH = 0; MH < 2; ++MH)                                             \
      _Pragma("unroll")                                                        \
      for (int mi = 0; mi < 4; ++mi)                                           \
        _Pragma("unroll")                                                      \
        for (int ni = 0; ni < 4; ++ni)                                         \
          acc[MH * 4 + mi][ni] = __builtin_amdgcn_mfma_f32_16x16x32_bf16(      \
              af[MH][mi], bv[ni], acc[MH * 4 + mi][ni], 0, 0, 0);              \
    __builtin_amdgcn_s_setprio(0);                                             \
    __builtin_amdgcn_s_barrier();                                              \
  }

  // ---- prologue: stage phases 0..2 (12 loads), wait for phase 0 ----
  STAGE_A(REG(0, 0, 0), 0, 0); STAGE_B(REG(0, 0, 1), 0, 0);
  STAGE_A(REG(0, 1, 0), 0, 1); STAGE_B(REG(0, 1, 1), 0, 1);
  STAGE_A(REG(1, 0, 0), 1, 0); STAGE_B(REG(1, 0, 1), 1, 0);
  VM8;
  __builtin_amdgcn_s_barrier();

  // ---- main loop: 15 iterations, 2 K-tiles each (tiles 0..29) ----
  for (int u = 0; u < 15; ++u) {
    int t1 = 2 * u + 1, t2 = 2 * u + 2, t3 = 2 * u + 3;
    PHASE(0, 0, { STAGE_A(REG(1,1,0), t1, 1); STAGE_B(REG(1,1,1), t1, 1); }, VM8);
    PHASE(0, 1, { STAGE_A(REG(0,0,0), t2, 0); STAGE_B(REG(0,0,1), t2, 0); }, VM8);
    PHASE(1, 0, { STAGE_A(REG(0,1,0), t2, 1); STAGE_B(REG(0,1,1), t2, 1); }, VM8);
    PHASE(1, 1, { STAGE_A(REG(1,0,0), t3, 0); STAGE_B(REG(1,0,1), t3, 0); }, VM8);
  }
  // ---- epilogue: tiles 30, 31 ----
  PHASE(0, 0, { STAGE_A(REG(1,1,0), 31, 1); STAGE_B(REG(1,1,1), 31, 1); }, VM8);
  PHASE(0, 1, , VM8);
  PHASE(1, 0, , VM4);
  PHASE(1, 1, , VM0);
#undef PHASE

  // ---- fused epilogue: bias + exact GELU + W2 contraction ----
  // acc element (mi,ni,j): row = wr*128+mi*16+lj*4+j, col = wn*64+ni*16+lr
  int q = nt * 4 + wn;
  float2* pOut = (float2*)part;
#pragma unroll
  for (int mi = 0; mi < 8; ++mi) {
    float s0[4] = {0.f, 0.f, 0.f, 0.f};
    float s1[4] = {0.f, 0.f, 0.f, 0.f};
#pragma unroll
    for (int ni = 0; ni < 4; ++ni) {
      int n = n0 + wn * 64 + ni * 16 + lr;
      float bb = b1[n];
      float2 wv = w2[n];
#pragma unroll
      for (int j = 0; j < 4; ++j) {
        float x = acc[mi][ni][j] + bb;
        float g = 0.5f * x * (1.0f + erff(x * 0.70710678118654752f));
        s0[j] += g * wv.x;
        s1[j] += g * wv.y;
      }
    }
#pragma unroll
    for (int off = 1; off < 16; off <<= 1) {
#pragma unroll
      for (int j = 0; j < 4; ++j) {
        s0[j] += __shfl_xor(s0[j], off, 64);
        s1[j] += __shfl_xor(s1[j], off, 64);
      }
    }
    if (lr == 0) {
#pragma unroll
      for (int j = 0; j < 4; ++j) {
        int m = m0 + wr * 128 + mi * 16 + lj * 4 + j;
        pOut[((size_t)q << 15) + m] = make_float2(s0[j], s1[j]);
      }
    }
  }
}

// ---- final reduce over 16 partials + b2 ---------------------------------
__global__ void reduce_k(const float2* __restrict__ part,
                         const float* __restrict__ b2,
                         float2* __restrict__ out) {
  int m = blockIdx.x * blockDim.x + threadIdx.x;
  if (m >= M_) return;
  float a0 = b2[0], a1 = b2[1];
#pragma unroll
  for (int q = 0; q < 16; ++q) {
    float2 v = part[((size_t)q << 15) + m];
    a0 += v.x; a1 += v.y;
  }
  out[m] = make_float2(a0, a1);
}

extern "C" void kernel_launch(void* const* d_in, const int* in_sizes, int n_in,
                              void* d_out, int out_size, void* d_ws, size_t ws_size,
                              hipStream_t stream) {
  const float* hidden = (const float*)d_in[0];
  const int*   pairs  = (const int*)d_in[1];
  const float* W1     = (const float*)d_in[2];
  const float* b1     = (const float*)d_in[3];
  const float* W2     = (const float*)d_in[4];
  const float* b2     = (const float*)d_in[5];
  float* out = (float*)d_out;

  // ws layout: hidden_bf16 (32 MiB) | W1T_bf16 (4 MiB) | partials (4 MiB)
  u16* hidB = (u16*)d_ws;
  u16* w1t  = hidB + (size_t)B_ * S_ * H_;
  float* part = (float*)(w1t + (size_t)H_ * K_);

  int n4 = (B_ * S_ * H_) / 4;
  cvt_hidden_k<<<4096, 256, 0, stream>>>((const float4*)hidden, (ushort4*)hidB, n4);
  transp_w1_k<<<dim3(H_ / 32, K_ / 32), dim3(32, 8), 0, stream>>>(W1, w1t);
  gemm_k<<<(M_ / 256) * (H_ / 256), 512, 0, stream>>>(
      hidB, w1t, pairs, b1, (const float2*)W2, part);
  reduce_k<<<(M_ + 255) / 256, 256, 0, stream>>>(
      (const float2*)part, b2, (float2*)out);
}